// Round 4
// baseline (1446.683 us; speedup 1.0000x reference)
//
#include <hip/hip_runtime.h>
#include <hip/hip_bf16.h>

// ---------------------------------------------------------------------------
// Fused 2-layer GRU + ReLU + Linear. One batch element per workgroup (256 WGs).
// Cross-layer pipelined: per step, phase M computes L2 gate pre-acts for time t
// AND L1 gate pre-acts for time t+1; phase E updates both states. 2 barriers.
// Round-4 change: 1024 threads (16 waves), 8-way k-split. Per-thread weights
// drop 156 -> 78 h2 regs, so the forced 128-VGPR tier (1024-thread block =>
// 4 waves/SIMD) actually FITS -- no AGPR overflow, no accvgpr moves per dot.
// Octet (8 lanes) owns rows {o, 128+o, 256+o} of both layers, k-split x8;
// partials summed by the E-phase reader via LDS.
// ---------------------------------------------------------------------------

typedef _Float16 h2 __attribute__((ext_vector_type(2)));

#if __has_builtin(__builtin_amdgcn_fdot2)
__device__ __forceinline__ float dot2f(h2 a, h2 b, float c) {
  return __builtin_amdgcn_fdot2(a, b, c, false);
}
#else
__device__ __forceinline__ float dot2f(h2 a, h2 b, float c) {
  return c + (float)a[0] * (float)b[0] + (float)a[1] * (float)b[1];
}
#endif

__device__ __forceinline__ h2 pack2(float x, float y) {
  h2 r; r[0] = (_Float16)x; r[1] = (_Float16)y; return r;
}
__device__ __forceinline__ float sigm(float x) {
  return 1.0f / (1.0f + __expf(-x));
}
__device__ __forceinline__ float tanh_f(float x) {
  x = fminf(fmaxf(x, -15.f), 15.f);
  float e = __expf(2.f * x);
  return (e - 1.f) / (e + 1.f);
}
__device__ __forceinline__ float hsum(float4 v) { return (v.x + v.y) + (v.z + v.w); }

__device__ __forceinline__ void load_pack8(const float* p, h2* w) {
  float4 a = ((const float4*)p)[0], b = ((const float4*)p)[1];
  w[0] = pack2(a.x, a.y); w[1] = pack2(a.z, a.w);
  w[2] = pack2(b.x, b.y); w[3] = pack2(b.z, b.w);
}

#define SEQ 1200
#define HID 128
#define INSZ 32

#define DOT4Q(W, F, ACC)                                                \
  ACC = dot2f((W)[0], __builtin_bit_cast(h2, (F).x), ACC);              \
  ACC = dot2f((W)[1], __builtin_bit_cast(h2, (F).y), ACC);              \
  ACC = dot2f((W)[2], __builtin_bit_cast(h2, (F).z), ACC);              \
  ACC = dot2f((W)[3], __builtin_bit_cast(h2, (F).w), ACC);

#define DOT8(W, FA, FB, ACC)                                            \
  DOT4Q(&(W)[0], FA, ACC) DOT4Q(&(W)[4], FB, ACC)

__global__ __launch_bounds__(1024) void gru_fused(
    const float* __restrict__ x,
    const float* __restrict__ Wih0, const float* __restrict__ Whh0,
    const float* __restrict__ bih0, const float* __restrict__ bhh0,
    const float* __restrict__ Wih1, const float* __restrict__ Whh1,
    const float* __restrict__ bih1, const float* __restrict__ bhh1,
    const float* __restrict__ Wlin, const float* __restrict__ blin,
    float* __restrict__ out)
{
  const int tid = threadIdx.x;
  const int b   = blockIdx.x;
  const int oct = tid >> 3;   // row-triplet 0..127 -> rows {oct, 128+oct, 256+oct}
  const int ko  = tid & 7;    // k-eighth within the row

  // gate pre-activation partials: [slot(4)][oct(128)][ko(8)] f32
  __shared__ float G1p[4 * 1024];  // layer1 (r, z, nx, nh)
  __shared__ float G2p[4 * 1024];  // layer2
  __shared__ float  s0f[HID], s1f[HID];        // fp32 master states
  __shared__ float4 s0h4[16], s1h4[16];        // packed fp16 states (128 halfs)
  __shared__ float4 xh[2][4];                  // packed fp16 x row, double buffer
  __shared__ float  pbf[32];                   // output partials, double buffer

  // ---- per-thread weight registers (packed fp16), all compile-time indexed ----
  h2 wi0[3][2];    // W_ih0 rows {oct,128+oct,256+oct}, eighth ko (4 elems)
  h2 wh0[3][8];    // W_hh0 row eighth (16 elems)
  h2 wi1[3][8];    // W_ih1 row eighth
  h2 wh1[3][8];    // W_hh1 row eighth
#pragma unroll
  for (int rr = 0; rr < 3; ++rr) {
    const int row = rr * HID + oct;
    float4 v = *(const float4*)(Wih0 + (size_t)row * INSZ + ko * 4);
    wi0[rr][0] = pack2(v.x, v.y); wi0[rr][1] = pack2(v.z, v.w);
#pragma unroll
    for (int c = 0; c < 2; ++c) {
      load_pack8(Whh0 + (size_t)row * HID + ko * 16 + c * 8, &wh0[rr][c * 4]);
      load_pack8(Wih1 + (size_t)row * HID + ko * 16 + c * 8, &wi1[rr][c * 4]);
      load_pack8(Whh1 + (size_t)row * HID + ko * 16 + c * 8, &wh1[rr][c * 4]);
    }
  }

  // E-phase per-thread constants
  float bA = 0.f, bB = 0.f, bC = 0.f, bD = 0.f, wl = 0.f;
  if (tid < 128) {                 // L2 updater for row-group tid
    bA = bih1[tid] + bhh1[tid];
    bB = bih1[HID + tid] + bhh1[HID + tid];
    bC = bih1[2 * HID + tid];
    bD = bhh1[2 * HID + tid];
    wl = Wlin[tid];
  } else if (tid < 256) {          // L1 updater
    const int i = tid - 128;
    bA = bih0[i] + bhh0[i];
    bB = bih0[HID + i] + bhh0[HID + i];
    bC = bih0[2 * HID + i];
    bD = bhh0[2 * HID + i];
  }
  const float blv = blin[0];

  // ---- init: zero states, pack x_0 into xh[0] ----
  if (tid < HID) { s0f[tid] = 0.f; s1f[tid] = 0.f; }
  if (tid < 64) { ((float*)s0h4)[tid] = 0.f; ((float*)s1h4)[tid] = 0.f; }
  const float2* xsrc = (const float2*)x + (size_t)b * SEQ * (INSZ / 2);
  if (tid < 16) {
    float2 v = xsrc[tid];
    ((h2*)xh[0])[tid] = pack2(v.x, v.y);
  }
  __syncthreads();

  float* outp = out + (size_t)b * SEQ;

  for (int t = -1; t < SEQ; ++t) {
    // ================= phase M: all matvec partials =================
    {
      const int buf = (t + 1) & 1;
      const float2 xq = ((const float2*)xh[buf])[ko];
      const h2 x0 = __builtin_bit_cast(h2, xq.x);
      const h2 x1 = __builtin_bit_cast(h2, xq.y);
      const float4 sA = s0h4[ko * 2], sB = s0h4[ko * 2 + 1];
      const float4 tA = s1h4[ko * 2], tB = s1h4[ko * 2 + 1];
      float a0 = 0.f, a1 = 0.f, a2 = 0.f, a3 = 0.f;
      a0 = dot2f(wi0[0][0], x0, a0); a0 = dot2f(wi0[0][1], x1, a0);
      DOT8(wh0[0], sA, sB, a0)                                  // L1 r (merged)
      a1 = dot2f(wi0[1][0], x0, a1); a1 = dot2f(wi0[1][1], x1, a1);
      DOT8(wh0[1], sA, sB, a1)                                  // L1 z (merged)
      a2 = dot2f(wi0[2][0], x0, a2); a2 = dot2f(wi0[2][1], x1, a2); // L1 n, x-part
      DOT8(wh0[2], sA, sB, a3)                                  // L1 n, h-part
      float c0 = 0.f, c1 = 0.f, c2 = 0.f, c3 = 0.f;
      DOT8(wi1[0], sA, sB, c0) DOT8(wh1[0], tA, tB, c0)
      DOT8(wi1[1], sA, sB, c1) DOT8(wh1[1], tA, tB, c1)
      DOT8(wi1[2], sA, sB, c2)
      DOT8(wh1[2], tA, tB, c3)
      G1p[tid] = a0; G1p[1024 + tid] = a1; G1p[2048 + tid] = a2; G1p[3072 + tid] = a3;
      G2p[tid] = c0; G2p[1024 + tid] = c1; G2p[2048 + tid] = c2; G2p[3072 + tid] = c3;
    }
    // x_{t+2} prefetch (issued here, packed in E by the same threads)
    float2 xn;
    if ((tid & ~15) == 256) {
      const int ti = (t + 2 < SEQ) ? t + 2 : SEQ - 1;
      xn = xsrc[(size_t)ti * 16 + (tid - 256)];
    }
    __syncthreads();

    // ================= phase E: state updates =================
    if (tid < 128) {
      if (t >= 0) {  // layer-2 update -> h2_t, output partials
        const float4* G4 = (const float4*)G2p;
        float ra = hsum(G4[2 * tid])       + hsum(G4[2 * tid + 1]);
        float za = hsum(G4[256 + 2 * tid]) + hsum(G4[257 + 2 * tid]);
        float xa = hsum(G4[512 + 2 * tid]) + hsum(G4[513 + 2 * tid]);
        float ha = hsum(G4[768 + 2 * tid]) + hsum(G4[769 + 2 * tid]);
        float r = sigm(ra + bA);
        float z = sigm(za + bB);
        float n = tanh_f(xa + bC + r * (ha + bD));
        float h = (1.f - z) * n + z * s1f[tid];
        s1f[tid] = h;
        ((_Float16*)s1h4)[tid] = (_Float16)h;
        float p = fmaxf(h, 0.f) * wl;
        p += __shfl_xor(p, 1, 64);
        p += __shfl_xor(p, 2, 64);
        p += __shfl_xor(p, 4, 64);
        if ((tid & 7) == 0) pbf[(t & 1) * 16 + (tid >> 3)] = p;
      }
    } else if (tid < 256) {  // layer-1 update -> h1_{t+1}
      const int i = tid - 128;
      const float4* G4 = (const float4*)G1p;
      float ra = hsum(G4[2 * i])       + hsum(G4[2 * i + 1]);
      float za = hsum(G4[256 + 2 * i]) + hsum(G4[257 + 2 * i]);
      float xa = hsum(G4[512 + 2 * i]) + hsum(G4[513 + 2 * i]);
      float ha = hsum(G4[768 + 2 * i]) + hsum(G4[769 + 2 * i]);
      float r = sigm(ra + bA);
      float z = sigm(za + bB);
      float n = tanh_f(xa + bC + r * (ha + bD));
      float h = (1.f - z) * n + z * s0f[i];
      s0f[i] = h;
      ((_Float16*)s0h4)[i] = (_Float16)h;
    } else if (tid < 272) {  // pack x_{t+2}
      ((h2*)xh[t & 1])[tid - 256] = pack2(xn.x, xn.y);
    } else if (tid == 320 && t >= 1) {  // store out[t-1] from previous partials
      const float4* p4 = (const float4*)(pbf + ((t - 1) & 1) * 16);
      outp[t - 1] = hsum(p4[0]) + hsum(p4[1]) + hsum(p4[2]) + hsum(p4[3]) + blv;
    }
    __syncthreads();
  }

  if (tid == 0) {
    const float4* p4 = (const float4*)(pbf + ((SEQ - 1) & 1) * 16);
    outp[SEQ - 1] = hsum(p4[0]) + hsum(p4[1]) + hsum(p4[2]) + hsum(p4[3]) + blv;
  }
}

extern "C" void kernel_launch(void* const* d_in, const int* in_sizes, int n_in,
                              void* d_out, int out_size, void* d_ws, size_t ws_size,
                              hipStream_t stream) {
  const float* x    = (const float*)d_in[0];
  const float* Wih0 = (const float*)d_in[1];
  const float* Whh0 = (const float*)d_in[2];
  const float* bih0 = (const float*)d_in[3];
  const float* bhh0 = (const float*)d_in[4];
  const float* Wih1 = (const float*)d_in[5];
  const float* Whh1 = (const float*)d_in[6];
  const float* bih1 = (const float*)d_in[7];
  const float* bhh1 = (const float*)d_in[8];
  const float* Wlin = (const float*)d_in[9];
  const float* blin = (const float*)d_in[10];
  float* outp = (float*)d_out;

  const int Bn = in_sizes[0] / (SEQ * INSZ);   // 256
  hipLaunchKernelGGL(gru_fused, dim3(Bn), dim3(1024), 0, stream,
                     x, Wih0, Whh0, bih0, bhh0,
                     Wih1, Whh1, bih1, bhh1, Wlin, blin, outp);
}

// Round 5
// 1337.737 us; speedup vs baseline: 1.0814x; 1.0814x over previous
//
#include <hip/hip_runtime.h>
#include <hip/hip_bf16.h>

// ---------------------------------------------------------------------------
// Fused 2-layer GRU + ReLU + Linear. One batch element per workgroup (256 WGs).
// Cross-layer pipelined: per step, phase M computes L2 gate pre-acts for time t
// AND L1 gate pre-acts for time t+1; phase E updates both states. 2 barriers.
// Round-5 change: force 1 block/CU via a 64KB LDS pad. The register allocator
// ignores waves_per_eu hints and shrinks arch VGPRs to reach the next
// occupancy tier (R2/R3: 128, R4: 64), spilling the weight array into AGPRs
// and paying a v_accvgpr_read per dot2. With LDS > 80KB only 1 block/CU fits
// at ANY register count, so the allocator has no occupancy reason to shrink
// below 256 -> the 156 weight half2s stay architectural.
// Work split: quad (4 lanes) owns rows {q, 128+q, 256+q} of both layers,
// k-split x4 across the quad; partials summed by the E-phase reader via LDS.
// ---------------------------------------------------------------------------

typedef _Float16 h2 __attribute__((ext_vector_type(2)));

#if __has_builtin(__builtin_amdgcn_fdot2)
__device__ __forceinline__ float dot2f(h2 a, h2 b, float c) {
  return __builtin_amdgcn_fdot2(a, b, c, false);
}
#else
__device__ __forceinline__ float dot2f(h2 a, h2 b, float c) {
  return c + (float)a[0] * (float)b[0] + (float)a[1] * (float)b[1];
}
#endif

__device__ __forceinline__ h2 pack2(float x, float y) {
  h2 r; r[0] = (_Float16)x; r[1] = (_Float16)y; return r;
}
__device__ __forceinline__ float sigm(float x) {
  return 1.0f / (1.0f + __expf(-x));
}
__device__ __forceinline__ float tanh_f(float x) {
  x = fminf(fmaxf(x, -15.f), 15.f);
  float e = __expf(2.f * x);
  return (e - 1.f) / (e + 1.f);
}
__device__ __forceinline__ float hsum(float4 v) { return (v.x + v.y) + (v.z + v.w); }

__device__ __forceinline__ void load_pack8(const float* p, h2* w) {
  float4 a = ((const float4*)p)[0], b = ((const float4*)p)[1];
  w[0] = pack2(a.x, a.y); w[1] = pack2(a.z, a.w);
  w[2] = pack2(b.x, b.y); w[3] = pack2(b.z, b.w);
}

#define SEQ 1200
#define HID 128
#define INSZ 32

#define DOT4Q(W, F, ACC)                                                \
  ACC = dot2f((W)[0], __builtin_bit_cast(h2, (F).x), ACC);              \
  ACC = dot2f((W)[1], __builtin_bit_cast(h2, (F).y), ACC);              \
  ACC = dot2f((W)[2], __builtin_bit_cast(h2, (F).z), ACC);              \
  ACC = dot2f((W)[3], __builtin_bit_cast(h2, (F).w), ACC);

#define DOT16Q(W, FA, FB, FC, FD, ACC)                                  \
  DOT4Q(&(W)[0],  FA, ACC) DOT4Q(&(W)[4],  FB, ACC)                     \
  DOT4Q(&(W)[8],  FC, ACC) DOT4Q(&(W)[12], FD, ACC)

__global__ __launch_bounds__(512, 1) void gru_fused(
    const float* __restrict__ x,
    const float* __restrict__ Wih0, const float* __restrict__ Whh0,
    const float* __restrict__ bih0, const float* __restrict__ bhh0,
    const float* __restrict__ Wih1, const float* __restrict__ Whh1,
    const float* __restrict__ bih1, const float* __restrict__ bhh1,
    const float* __restrict__ Wlin, const float* __restrict__ blin,
    float* __restrict__ out)
{
  const int tid = threadIdx.x;
  const int b   = blockIdx.x;
  const int q   = tid >> 2;   // quad id 0..127 -> rows {q, 128+q, 256+q}
  const int ql  = tid & 3;    // k-quarter within the row

  // gate pre-activation partials: [slot(4)][quad(128)][lane(4)] f32
  __shared__ float G1p[4 * 512];   // layer1 (r, z, nx, nh)
  __shared__ float G2p[4 * 512];   // layer2
  __shared__ float  s0f[HID], s1f[HID];        // fp32 master states
  __shared__ float4 s0h4[16], s1h4[16];        // packed fp16 states (128 halfs)
  __shared__ float4 xh[2][4];                  // packed fp16 x row, double buffer
  __shared__ float  pbf[32];                   // output partials, double buffer
  // Occupancy clamp: push LDS/block past 80KB so only ONE block fits per CU,
  // at any VGPR count. This removes the allocator's incentive to shrink arch
  // VGPRs (and spill weights to AGPRs) to reach a higher-occupancy tier.
  __shared__ float ldspad[16384];              // 64 KB

  // ---- per-thread weight registers (packed fp16), all compile-time indexed ----
  h2 wi0[3][4];    // W_ih0 rows {q,128+q,256+q}, quarter ql (8 elems each)
  h2 wh0[3][16];   // W_hh0 rows, quarter ql (32 elems each)
  h2 wi1[3][16];   // W_ih1 rows
  h2 wh1[3][16];   // W_hh1 rows
#pragma unroll
  for (int rr = 0; rr < 3; ++rr) {
    const int row = rr * HID + q;
    load_pack8(Wih0 + (size_t)row * INSZ + ql * 8, wi0[rr]);
#pragma unroll
    for (int c = 0; c < 4; ++c) {
      load_pack8(Whh0 + (size_t)row * HID + ql * 32 + c * 8, &wh0[rr][c * 4]);
      load_pack8(Wih1 + (size_t)row * HID + ql * 32 + c * 8, &wi1[rr][c * 4]);
      load_pack8(Whh1 + (size_t)row * HID + ql * 32 + c * 8, &wh1[rr][c * 4]);
    }
  }

  // E-phase per-thread constants
  float bA = 0.f, bB = 0.f, bC = 0.f, bD = 0.f, wl = 0.f;
  if (tid < 128) {                 // L2 updater for row-group tid
    bA = bih1[tid] + bhh1[tid];
    bB = bih1[HID + tid] + bhh1[HID + tid];
    bC = bih1[2 * HID + tid];
    bD = bhh1[2 * HID + tid];
    wl = Wlin[tid];
  } else if (tid < 256) {          // L1 updater
    const int i = tid - 128;
    bA = bih0[i] + bhh0[i];
    bB = bih0[HID + i] + bhh0[HID + i];
    bC = bih0[2 * HID + i];
    bD = bhh0[2 * HID + i];
  }
  const float blv = blin[0];

  // keep the pad allocated (volatile store cannot be eliminated)
  if (tid == 511) {
    volatile float* vp = ldspad;
    vp[0] = blv;
  }

  // ---- init: zero states, pack x_0 into xh[0] ----
  if (tid < HID) { s0f[tid] = 0.f; s1f[tid] = 0.f; }
  if (tid < 64) { ((float*)s0h4)[tid] = 0.f; ((float*)s1h4)[tid] = 0.f; }
  const float2* xsrc = (const float2*)x + (size_t)b * SEQ * (INSZ / 2);
  if (tid < 16) {
    float2 v = xsrc[tid];
    ((h2*)xh[0])[tid] = pack2(v.x, v.y);
  }
  __syncthreads();

  float* outp = out + (size_t)b * SEQ;

  for (int t = -1; t < SEQ; ++t) {
    // ================= phase M: all matvec partials =================
    {
      const int buf = (t + 1) & 1;
      const float4 xq = xh[buf][ql];
      const float4 sA = s0h4[ql * 4 + 0], sB = s0h4[ql * 4 + 1],
                   sC = s0h4[ql * 4 + 2], sD = s0h4[ql * 4 + 3];
      const float4 tA = s1h4[ql * 4 + 0], tB = s1h4[ql * 4 + 1],
                   tC = s1h4[ql * 4 + 2], tD = s1h4[ql * 4 + 3];
      float a0 = 0.f, a1 = 0.f, a2 = 0.f, a3 = 0.f;
      DOT4Q(wi0[0], xq, a0) DOT16Q(wh0[0], sA, sB, sC, sD, a0)   // L1 r (merged)
      DOT4Q(wi0[1], xq, a1) DOT16Q(wh0[1], sA, sB, sC, sD, a1)   // L1 z (merged)
      DOT4Q(wi0[2], xq, a2)                                      // L1 n, x-part
      DOT16Q(wh0[2], sA, sB, sC, sD, a3)                         // L1 n, h-part
      float c0 = 0.f, c1 = 0.f, c2 = 0.f, c3 = 0.f;
      DOT16Q(wi1[0], sA, sB, sC, sD, c0) DOT16Q(wh1[0], tA, tB, tC, tD, c0)
      DOT16Q(wi1[1], sA, sB, sC, sD, c1) DOT16Q(wh1[1], tA, tB, tC, tD, c1)
      DOT16Q(wi1[2], sA, sB, sC, sD, c2)
      DOT16Q(wh1[2], tA, tB, tC, tD, c3)
      G1p[tid] = a0; G1p[512 + tid] = a1; G1p[1024 + tid] = a2; G1p[1536 + tid] = a3;
      G2p[tid] = c0; G2p[512 + tid] = c1; G2p[1024 + tid] = c2; G2p[1536 + tid] = c3;
    }
    // x_{t+2} prefetch (issued here, packed in E by the same threads)
    float2 xn;
    if ((tid & ~15) == 256) {
      const int ti = (t + 2 < SEQ) ? t + 2 : SEQ - 1;
      xn = xsrc[(size_t)ti * 16 + (tid - 256)];
    }
    __syncthreads();

    // ================= phase E: state updates =================
    if (tid < 128) {
      if (t >= 0) {  // layer-2 update -> h2_t, output partials
        const float4* G4 = (const float4*)G2p;
        float4 r4 = G4[tid], z4 = G4[128 + tid], x4 = G4[256 + tid], h4 = G4[384 + tid];
        float r = sigm(hsum(r4) + bA);
        float z = sigm(hsum(z4) + bB);
        float n = tanh_f(hsum(x4) + bC + r * (hsum(h4) + bD));
        float h = (1.f - z) * n + z * s1f[tid];
        s1f[tid] = h;
        ((_Float16*)s1h4)[tid] = (_Float16)h;
        float p = fmaxf(h, 0.f) * wl;
        p += __shfl_xor(p, 1, 64);
        p += __shfl_xor(p, 2, 64);
        p += __shfl_xor(p, 4, 64);
        if ((tid & 7) == 0) pbf[(t & 1) * 16 + (tid >> 3)] = p;
      }
    } else if (tid < 256) {  // layer-1 update -> h1_{t+1}
      const int i = tid - 128;
      const float4* G4 = (const float4*)G1p;
      float4 r4 = G4[i], z4 = G4[128 + i], x4 = G4[256 + i], h4 = G4[384 + i];
      float r = sigm(hsum(r4) + bA);
      float z = sigm(hsum(z4) + bB);
      float n = tanh_f(hsum(x4) + bC + r * (hsum(h4) + bD));
      float h = (1.f - z) * n + z * s0f[i];
      s0f[i] = h;
      ((_Float16*)s0h4)[i] = (_Float16)h;
    } else if (tid < 272) {  // pack x_{t+2}
      ((h2*)xh[t & 1])[tid - 256] = pack2(xn.x, xn.y);
    } else if (tid == 320 && t >= 1) {  // store out[t-1] from previous partials
      const float4* p4 = (const float4*)(pbf + ((t - 1) & 1) * 16);
      outp[t - 1] = hsum(p4[0]) + hsum(p4[1]) + hsum(p4[2]) + hsum(p4[3]) + blv;
    }
    __syncthreads();
  }

  if (tid == 0) {
    const float4* p4 = (const float4*)(pbf + ((SEQ - 1) & 1) * 16);
    outp[SEQ - 1] = hsum(p4[0]) + hsum(p4[1]) + hsum(p4[2]) + hsum(p4[3]) + blv;
  }
}

extern "C" void kernel_launch(void* const* d_in, const int* in_sizes, int n_in,
                              void* d_out, int out_size, void* d_ws, size_t ws_size,
                              hipStream_t stream) {
  const float* x    = (const float*)d_in[0];
  const float* Wih0 = (const float*)d_in[1];
  const float* Whh0 = (const float*)d_in[2];
  const float* bih0 = (const float*)d_in[3];
  const float* bhh0 = (const float*)d_in[4];
  const float* Wih1 = (const float*)d_in[5];
  const float* Whh1 = (const float*)d_in[6];
  const float* bih1 = (const float*)d_in[7];
  const float* bhh1 = (const float*)d_in[8];
  const float* Wlin = (const float*)d_in[9];
  const float* blin = (const float*)d_in[10];
  float* outp = (float*)d_out;

  const int Bn = in_sizes[0] / (SEQ * INSZ);   // 256
  hipLaunchKernelGGL(gru_fused, dim3(Bn), dim3(512), 0, stream,
                     x, Wih0, Whh0, bih0, bhh0,
                     Wih1, Whh1, bih1, bhh1, Wlin, blin, outp);
}